// Round 17
// baseline (312.737 us; speedup 1.0000x reference)
//
#include <hip/hip_runtime.h>

#define NN 20000
#define NE 640000
#define HD 128
#define NL 3
#define NG 128
#define NC 2
#define BN_EPS 1e-5f
#define NR 4            // stat replicas (atomic spread)
#define AST 136
#define NB 157          // dst buckets (dst >> 7), 128 nodes each
#define BCAP 6144       // records per bucket (mean 4076, +32 sigma)

typedef __attribute__((ext_vector_type(4))) float f32x4;
typedef __attribute__((ext_vector_type(8))) _Float16 f16x8;

// ---------- fused setup: weight fp16-split prep + p/q + edge bucketize ----------
__global__ void k_setup(const float* __restrict__ encW, const float* __restrict__ encb,
                        const float* __restrict__ W1, const float* __restrict__ W2,
                        const int* __restrict__ ei,
                        _Float16* __restrict__ Wt, float* __restrict__ pq,
                        int2* __restrict__ brec, int* __restrict__ gcur) {
    __shared__ int cnt[NB];
    __shared__ int base[NB];
    int b = blockIdx.x, tid = threadIdx.x;
    if (b < 48) {
        int t = b * 256 + tid;                 // 6*2048 = 12288
        if (t >= 6 * 2048) return;
        int mat = t >> 11;
        int rem = t & 2047;
        int n  = rem >> 4;
        int k0 = (rem & 15) * 8;
        int l  = mat >> 1;
        const float* src = (mat & 1) ? (W2 + l * HD * HD) : (W1 + l * HD * HD);
        _Float16* dhi = Wt + mat * HD * HD;
        _Float16* dlo = Wt + (6 + mat) * HD * HD;
        f16x8 hi, lo;
#pragma unroll
        for (int j = 0; j < 8; j++) {
            float w = src[(k0 + j) * HD + n];
            _Float16 hh = (_Float16)w;
            hi[j] = hh;
            lo[j] = (_Float16)((w - (float)hh) * 1024.0f);
        }
        *(f16x8*)&dhi[n * HD + k0] = hi;
        *(f16x8*)&dlo[n * HD + k0] = lo;
    } else if (b == 48) {
        if (tid < HD) {
            float ps = 0.f, qs = 0.f;
            for (int k = 0; k < HD; k++) {
                float w = W1[k * HD + tid];
                ps = fmaf(encW[k], w, ps);
                qs = fmaf(encb[k], w, qs);
            }
            pq[tid] = ps;
            pq[HD + tid] = qs;
        }
    } else {
        int bb = b - 49;                       // 0..499, 1280 edges each (exact)
        for (int i = tid; i < NB; i += 256) cnt[i] = 0;
        __syncthreads();
        int src[5], dst[5];
#pragma unroll
        for (int j = 0; j < 5; j++) {
            int e = bb * 1280 + j * 256 + tid;
            src[j] = ei[e];
            dst[j] = ei[NE + e];
            atomicAdd(&cnt[dst[j] >> 7], 1);
        }
        __syncthreads();
        for (int i = tid; i < NB; i += 256) {
            base[i] = atomicAdd(&gcur[i], cnt[i]);
            cnt[i] = 0;
        }
        __syncthreads();
#pragma unroll
        for (int j = 0; j < 5; j++) {
            int bk = dst[j] >> 7;
            int pos = base[bk] + atomicAdd(&cnt[bk], 1);
            brec[bk * BCAP + pos] = make_int2(src[j], dst[j]);
        }
    }
}

// ---------- CSR finalize + layer-0 scalar aggregation, per bucket ----------
// count + Sx-accumulate + scan + fill + (a,d,scal moments) in one kernel.
__global__ void k_csr(const int2* __restrict__ brec, const int* __restrict__ gcur,
                      const float* __restrict__ x, const float* __restrict__ eps_gin,
                      int* __restrict__ row_ptr, int* __restrict__ csr_src,
                      float* __restrict__ av, float* __restrict__ dv,
                      float* __restrict__ scal) {
    __shared__ int lc[128];
    __shared__ float sx[128];
    __shared__ int pfx[128];
    __shared__ int sbase[4];
    __shared__ int cur[128];
    int b = blockIdx.x, tid = threadIdx.x;
    if (tid < 128) { lc[tid] = 0; sx[tid] = 0.f; }
    __syncthreads();
    int nrec = gcur[b];
    const int2* rec = brec + b * BCAP;
    for (int r = tid; r < nrec; r += 256) {
        int2 rc = rec[r];
        atomicAdd(&lc[rc.y & 127], 1);
        atomicAdd(&sx[rc.y & 127], x[rc.x]);
    }
    // bucket base = sum gcur[0..b)
    int v = (tid < b) ? gcur[tid] : 0;     // b <= 156 < 256
    v += __shfl_xor(v, 1);  v += __shfl_xor(v, 2);  v += __shfl_xor(v, 4);
    v += __shfl_xor(v, 8);  v += __shfl_xor(v, 16); v += __shfl_xor(v, 32);
    if ((tid & 63) == 0) sbase[tid >> 6] = v;
    __syncthreads();
    int base0 = sbase[0] + sbase[1] + sbase[2] + sbase[3];
    if (tid < 128) pfx[tid] = lc[tid];
    __syncthreads();
    for (int off = 1; off < 128; off <<= 1) {
        int t = (tid < 128 && tid >= off) ? pfx[tid - off] : 0;
        __syncthreads();
        if (tid < 128) pfx[tid] += t;
        __syncthreads();
    }
    if (tid < 128) {
        int node = b * 128 + tid;
        int e = base0 + pfx[tid] - lc[tid];   // exclusive
        if (node < NN) { row_ptr[node] = e; cur[tid] = e; }
    }
    if (b == NB - 1 && tid == 0) row_ptr[NN] = NE;
    __syncthreads();
    for (int r = tid; r < nrec; r += 256) {
        int2 rc = rec[r];
        int pos = atomicAdd(&cur[rc.y & 127], 1);
        csr_src[pos] = rc.x;
    }
    // layer-0 scalars: a = (1+eps)*x[n] + Sx, d = (1+eps) + deg
    __syncthreads();
    float a = 0.f, d = 0.f;
    if (tid < 128) {
        int node = b * 128 + tid;
        if (node < NN) {
            float e = 1.0f + eps_gin[0];
            a = fmaf(e, x[node], sx[tid]);
            d = e + (float)lc[tid];
            av[node] = a;
            dv[node] = d;
        }
    }
    float vv[5] = { a, d, a * a, d * d, a * d };
#pragma unroll
    for (int j = 0; j < 5; j++) {
        float t = vv[j];
        t += __shfl_xor(t, 1);  t += __shfl_xor(t, 2);  t += __shfl_xor(t, 4);
        t += __shfl_xor(t, 8);  t += __shfl_xor(t, 16); t += __shfl_xor(t, 32);
        vv[j] = t;
    }
    if ((tid & 63) == 0 && tid < 128)
#pragma unroll
        for (int j = 0; j < 5; j++) atomicAdd(&scal[j], vv[j]);
}

// ---------- layer-0 GEMM2: rank-2 A, analytic BN, 3-term split, 32-row tile ----------
__global__ __launch_bounds__(256) void k_gemmA(
    const float* __restrict__ av, const float* __restrict__ dv,
    const float* __restrict__ pq, const float* __restrict__ scal,
    const float* __restrict__ gamma, const float* __restrict__ beta,
    const _Float16* __restrict__ Whi, const _Float16* __restrict__ Wlo,
    _Float16* __restrict__ out0, _Float16* __restrict__ out1,
    float* __restrict__ stat_out) {
    __shared__ __align__(16) _Float16 AsH[32 * AST];
    __shared__ __align__(16) _Float16 AsL[32 * AST];
    int tid  = threadIdx.x;
    int wave = tid >> 6, lane = tid & 63;
    int quad = lane >> 4, l16 = lane & 15;
    int r0   = blockIdx.x * 32;               // 625 blocks, no guards
    int n0w  = wave * 32;
    int rep  = (blockIdx.x & (NR - 1)) * 256;

    f16x8 bhi[2][4], blo[2][4];
#pragma unroll
    for (int nt = 0; nt < 2; nt++) {
        int n = n0w + nt * 16 + l16;
#pragma unroll
        for (int kq = 0; kq < 4; kq++) {
            int k = kq * 32 + quad * 8;
            bhi[nt][kq] = *(const f16x8*)&Whi[n * HD + k];
            blo[nt][kq] = *(const f16x8*)&Wlo[n * HD + k];
        }
    }

    {
        int c8 = (tid & 15) * 8;
        int nl = tid >> 4;
        float Sa = scal[0], Sd = scal[1], Saa = scal[2], Sdd = scal[3], Sad = scal[4];
        float pj[8], qj[8], sc[8], sh[8];
#pragma unroll
        for (int j = 0; j < 8; j++) {
            float P = pq[c8 + j], Q = pq[HD + c8 + j];
            pj[j] = P; qj[j] = Q;
            float mu  = (Sa * P + Sd * Q) * (1.0f / NN);
            float ex2 = (Saa * P * P + 2.f * Sad * P * Q + Sdd * Q * Q) * (1.0f / NN);
            float var = ex2 - mu * mu;
            float g = gamma[c8 + j] * rsqrtf(var + BN_EPS);
            sc[j] = g;
            sh[j] = beta[c8 + j] - g * mu;
        }
#pragma unroll
        for (int i = 0; i < 2; i++) {
            int r = i * 16 + nl;
            int row = r0 + r;
            float a = av[row], d = dv[row];
            f16x8 hh, ll;
#pragma unroll
            for (int j = 0; j < 8; j++) {
                float t0 = fmaf(a, pj[j], d * qj[j]);
                float v = fmaxf(fmaf(sc[j], t0, sh[j]), 0.f);
                _Float16 h = (_Float16)v;
                hh[j] = h;
                ll[j] = (_Float16)((v - (float)h) * 512.0f);
            }
            *(f16x8*)&AsH[r * AST + c8] = hh;
            *(f16x8*)&AsL[r * AST + c8] = ll;
        }
    }
    __syncthreads();

    f32x4 ahh[2][2], ahl[2][2], alh[2][2];
#pragma unroll
    for (int mt = 0; mt < 2; mt++)
#pragma unroll
        for (int nt = 0; nt < 2; nt++)
#pragma unroll
            for (int e2 = 0; e2 < 4; e2++) {
                ahh[mt][nt][e2] = 0.f; ahl[mt][nt][e2] = 0.f; alh[mt][nt][e2] = 0.f;
            }

#pragma unroll
    for (int mt = 0; mt < 2; mt++) {
        int mrow = mt * 16 + l16;
#pragma unroll
        for (int kq = 0; kq < 4; kq++) {
            f16x8 ah = *(const f16x8*)&AsH[mrow * AST + kq * 32 + quad * 8];
            f16x8 al = *(const f16x8*)&AsL[mrow * AST + kq * 32 + quad * 8];
#pragma unroll
            for (int nt = 0; nt < 2; nt++) {
                ahh[mt][nt] = __builtin_amdgcn_mfma_f32_16x16x32_f16(ah, bhi[nt][kq], ahh[mt][nt], 0, 0, 0);
                ahl[mt][nt] = __builtin_amdgcn_mfma_f32_16x16x32_f16(ah, blo[nt][kq], ahl[mt][nt], 0, 0, 0);
                alh[mt][nt] = __builtin_amdgcn_mfma_f32_16x16x32_f16(al, bhi[nt][kq], alh[mt][nt], 0, 0, 0);
            }
        }
    }

    float s[2] = { 0.f, 0.f }, q[2] = { 0.f, 0.f };
#pragma unroll
    for (int mt = 0; mt < 2; mt++) {
        int rbase = r0 + mt * 16 + quad * 4;
#pragma unroll
        for (int rr = 0; rr < 4; rr++) {
            int row = rbase + rr;
#pragma unroll
            for (int nt = 0; nt < 2; nt++) {
                float v = ahh[mt][nt][rr] + ahl[mt][nt][rr] * (1.0f / 1024.0f)
                        + alh[mt][nt][rr] * (1.0f / 512.0f);
                int col = n0w + nt * 16 + l16;
                _Float16* dst = (col < 64) ? out0 : out1;
                dst[row * 64 + (col & 63)] = (_Float16)v;
                s[nt] += v;
                q[nt] = fmaf(v, v, q[nt]);
            }
        }
    }
#pragma unroll
    for (int nt = 0; nt < 2; nt++) {
        float ss = s[nt], qq = q[nt];
        ss += __shfl_xor(ss, 16); ss += __shfl_xor(ss, 32);
        qq += __shfl_xor(qq, 16); qq += __shfl_xor(qq, 32);
        if (lane < 16) {
            atomicAdd(&stat_out[rep + n0w + nt * 16 + lane], ss);
            atomicAdd(&stat_out[rep + 128 + n0w + nt * 16 + lane], qq);
        }
    }
}

// ---------- aggregation: channel-halved fp16 gather, 16-deep unroll ----------
// Grid 1250: blocks [0,625) process half 0 (ch 0-63), [625,1250) half 1.
__global__ void k_aggr(const int* __restrict__ row_ptr, const int* __restrict__ csr_src,
                       const _Float16* __restrict__ u0, const _Float16* __restrict__ u1,
                       const float* __restrict__ stat_in,
                       const float* __restrict__ gamma, const float* __restrict__ beta,
                       const float* __restrict__ eps_gin, int l,
                       float* __restrict__ z) {
    int i = blockIdx.x * blockDim.x + threadIdx.x;   // 2 * NN*8
    if (i >= NN * 16) return;
    int half = (i >= NN * 8) ? 1 : 0;
    int j    = i - half * NN * 8;
    int n    = j >> 3;
    int c8in = (j & 7) * 8;
    int c8   = half * 64 + c8in;
    const _Float16* u = half ? u1 : u0;
    float e = 1.0f + eps_gin[l];
    float sc[8], sh[8];
#pragma unroll
    for (int jj = 0; jj < 8; jj++) {
        float ssum = 0.f, ssq = 0.f;
#pragma unroll
        for (int r = 0; r < NR; r++) {
            ssum += stat_in[r * 256 + c8 + jj];
            ssq  += stat_in[r * 256 + 128 + c8 + jj];
        }
        float mu  = ssum * (1.0f / NN);
        float var = ssq * (1.0f / NN) - mu * mu;
        float a = gamma[c8 + jj] * rsqrtf(var + BN_EPS);
        sc[jj] = a;
        sh[jj] = beta[c8 + jj] - a * mu;
    }
    float acc[8];
    {
        f16x8 r = *(const f16x8*)&u[n * 64 + c8in];
#pragma unroll
        for (int jj = 0; jj < 8; jj++)
            acc[jj] = e * fmaxf(fmaf(sc[jj], (float)r[jj], sh[jj]), 0.f);
    }
    int p = row_ptr[n], end = row_ptr[n + 1];
    for (; p + 15 < end; p += 16) {
        f16x8 r[16];
#pragma unroll
        for (int jj = 0; jj < 16; jj++) r[jj] = *(const f16x8*)&u[csr_src[p + jj] * 64 + c8in];
#pragma unroll
        for (int jj = 0; jj < 16; jj++)
#pragma unroll
            for (int q = 0; q < 8; q++)
                acc[q] += fmaxf(fmaf(sc[q], (float)r[jj][q], sh[q]), 0.f);
    }
    if (p + 7 < end) {
        f16x8 r[8];
#pragma unroll
        for (int jj = 0; jj < 8; jj++) r[jj] = *(const f16x8*)&u[csr_src[p + jj] * 64 + c8in];
#pragma unroll
        for (int jj = 0; jj < 8; jj++)
#pragma unroll
            for (int q = 0; q < 8; q++)
                acc[q] += fmaxf(fmaf(sc[q], (float)r[jj][q], sh[q]), 0.f);
        p += 8;
    }
    for (; p < end; p++) {
        f16x8 r = *(const f16x8*)&u[csr_src[p] * 64 + c8in];
#pragma unroll
        for (int q = 0; q < 8; q++)
            acc[q] += fmaxf(fmaf(sc[q], (float)r[q], sh[q]), 0.f);
    }
    float4 o0 = { acc[0], acc[1], acc[2], acc[3] };
    float4 o1 = { acc[4], acc[5], acc[6], acc[7] };
    *(float4*)&z[n * HD + c8]     = o0;
    *(float4*)&z[n * HD + c8 + 4] = o1;
}

// ---------- fp16-MFMA GEMM, 32-row tile, fp32 A, 3-term split ----------
// OUTF16: channel-split fp16 outputs (out0/out1); else fp32 full-width outv.
template <bool BNRELU, bool OUTF16>
__global__ __launch_bounds__(256) void k_gemm(
    const float* __restrict__ A,
    const _Float16* __restrict__ Whi, const _Float16* __restrict__ Wlo,
    const float* __restrict__ stat_in,
    const float* __restrict__ gamma, const float* __restrict__ beta,
    void* __restrict__ outv, _Float16* __restrict__ out1,
    float* __restrict__ stat_out) {
    __shared__ __align__(16) _Float16 AsH[32 * AST];
    __shared__ __align__(16) _Float16 AsL[32 * AST];
    int tid  = threadIdx.x;
    int wave = tid >> 6, lane = tid & 63;
    int quad = lane >> 4, l16 = lane & 15;
    int r0   = blockIdx.x * 32;               // 625 blocks: no guards
    int n0w  = wave * 32;
    int rep  = (blockIdx.x & (NR - 1)) * 256;

    f16x8 bhi[2][4], blo[2][4];
#pragma unroll
    for (int nt = 0; nt < 2; nt++) {
        int n = n0w + nt * 16 + l16;
#pragma unroll
        for (int kq = 0; kq < 4; kq++) {
            int k = kq * 32 + quad * 8;
            bhi[nt][kq] = *(const f16x8*)&Whi[n * HD + k];
            blo[nt][kq] = *(const f16x8*)&Wlo[n * HD + k];
        }
    }

    {
        int c8 = (tid & 15) * 8;
        int nl = tid >> 4;
        float sc[8], sh[8];
        if (BNRELU) {
#pragma unroll
            for (int j = 0; j < 8; j++) {
                float ssum = 0.f, ssq = 0.f;
#pragma unroll
                for (int r = 0; r < NR; r++) {
                    ssum += stat_in[r * 256 + c8 + j];
                    ssq  += stat_in[r * 256 + 128 + c8 + j];
                }
                float mu  = ssum * (1.0f / NN);
                float var = ssq * (1.0f / NN) - mu * mu;
                float a = gamma[c8 + j] * rsqrtf(var + BN_EPS);
                sc[j] = a;
                sh[j] = beta[c8 + j] - a * mu;
            }
        }
#pragma unroll
        for (int i = 0; i < 2; i++) {
            int r = i * 16 + nl;
            int row = r0 + r;
            float4 a0 = *(const float4*)&A[row * HD + c8];
            float4 a1 = *(const float4*)&A[row * HD + c8 + 4];
            float av8[8] = { a0.x, a0.y, a0.z, a0.w, a1.x, a1.y, a1.z, a1.w };
            f16x8 hh, ll;
#pragma unroll
            for (int j = 0; j < 8; j++) {
                float a = av8[j];
                if (BNRELU) a = fmaxf(fmaf(sc[j], a, sh[j]), 0.f);
                _Float16 h = (_Float16)a;
                hh[j] = h;
                ll[j] = (_Float16)((a - (float)h) * 512.0f);
            }
            *(f16x8*)&AsH[r * AST + c8] = hh;
            *(f16x8*)&AsL[r * AST + c8] = ll;
        }
    }
    __syncthreads();

    f32x4 ahh[2][2], ahl[2][2], alh[2][2];
#pragma unroll
    for (int mt = 0; mt < 2; mt++)
#pragma unroll
        for (int nt = 0; nt < 2; nt++)
#pragma unroll
            for (int e2 = 0; e2 < 4; e2++) {
                ahh[mt][nt][e2] = 0.f; ahl[mt][nt][e2] = 0.f; alh[mt][nt][e2] = 0.f;
            }

#pragma unroll
    for (int mt = 0; mt < 2; mt++) {
        int mrow = mt * 16 + l16;
#pragma unroll
        for (int kq = 0; kq < 4; kq++) {
            f16x8 ah = *(const f16x8*)&AsH[mrow * AST + kq * 32 + quad * 8];
            f16x8 al = *(const f16x8*)&AsL[mrow * AST + kq * 32 + quad * 8];
#pragma unroll
            for (int nt = 0; nt < 2; nt++) {
                ahh[mt][nt] = __builtin_amdgcn_mfma_f32_16x16x32_f16(ah, bhi[nt][kq], ahh[mt][nt], 0, 0, 0);
                ahl[mt][nt] = __builtin_amdgcn_mfma_f32_16x16x32_f16(ah, blo[nt][kq], ahl[mt][nt], 0, 0, 0);
                alh[mt][nt] = __builtin_amdgcn_mfma_f32_16x16x32_f16(al, bhi[nt][kq], alh[mt][nt], 0, 0, 0);
            }
        }
    }

    float s[2] = { 0.f, 0.f }, q[2] = { 0.f, 0.f };
#pragma unroll
    for (int mt = 0; mt < 2; mt++) {
        int rbase = r0 + mt * 16 + quad * 4;
#pragma unroll
        for (int rr = 0; rr < 4; rr++) {
            int row = rbase + rr;
#pragma unroll
            for (int nt = 0; nt < 2; nt++) {
                float v = ahh[mt][nt][rr] + ahl[mt][nt][rr] * (1.0f / 1024.0f)
                        + alh[mt][nt][rr] * (1.0f / 512.0f);
                int col = n0w + nt * 16 + l16;
                if (OUTF16) {
                    _Float16* dst = (col < 64) ? (_Float16*)outv : out1;
                    dst[row * 64 + (col & 63)] = (_Float16)v;
                } else {
                    ((float*)outv)[row * HD + col] = v;
                }
                s[nt] += v;
                q[nt] = fmaf(v, v, q[nt]);
            }
        }
    }
#pragma unroll
    for (int nt = 0; nt < 2; nt++) {
        float ss = s[nt], qq = q[nt];
        ss += __shfl_xor(ss, 16); ss += __shfl_xor(ss, 32);
        qq += __shfl_xor(qq, 16); qq += __shfl_xor(qq, 32);
        if (lane < 16) {
            atomicAdd(&stat_out[rep + n0w + nt * 16 + lane], ss);
            atomicAdd(&stat_out[rep + 128 + n0w + nt * 16 + lane], qq);
        }
    }
}

// ---------- pool + classifier (split fp16 u, inline BN) ----------
__global__ __launch_bounds__(256) void k_pool(
    const _Float16* __restrict__ u0, const _Float16* __restrict__ u1,
    const float* __restrict__ stat_in,
    const float* __restrict__ gamma, const float* __restrict__ beta,
    const int* __restrict__ batch, const float* __restrict__ Wc,
    const float* __restrict__ bc, float* __restrict__ out) {
    __shared__ float part[2][HD];
    __shared__ float pooled[HD];
    __shared__ int range[2];
    int g = blockIdx.x;
    int tid = threadIdx.x;
    if (tid < 2) {
        int target = g + tid;
        int lo = 0, hi = NN;
        while (lo < hi) {
            int mid = (lo + hi) >> 1;
            if (batch[mid] < target) lo = mid + 1; else hi = mid;
        }
        range[tid] = lo;
    }
    __syncthreads();
    int start = range[0], end = range[1];
    int c    = tid & (HD - 1);
    int half = tid >> 7;
    const _Float16* uh = (c < 64) ? u0 : u1;
    int cin = c & 63;
    float ssum = 0.f, ssq = 0.f;
#pragma unroll
    for (int r = 0; r < NR; r++) {
        ssum += stat_in[r * 256 + c];
        ssq  += stat_in[r * 256 + 128 + c];
    }
    float mu  = ssum * (1.0f / NN);
    float var = ssq * (1.0f / NN) - mu * mu;
    float sc = gamma[c] * rsqrtf(var + BN_EPS);
    float sh = beta[c] - sc * mu;
    float acc = 0.f;
    for (int n = start + half; n < end; n += 2)
        acc += fmaxf(fmaf(sc, (float)uh[n * 64 + cin], sh), 0.f);
    part[half][c] = acc;
    __syncthreads();
    if (tid < HD) {
        float inv = 1.0f / fmaxf((float)(end - start), 1.0f);
        pooled[tid] = (part[0][tid] + part[1][tid]) * inv;
    }
    __syncthreads();
    if (tid < NC) {
        float a = bc[tid];
        for (int k = 0; k < HD; k++)
            a = fmaf(pooled[k], Wc[k * NC + tid], a);
        out[g * NC + tid] = a;
    }
}

extern "C" void kernel_launch(void* const* d_in, const int* in_sizes, int n_in,
                              void* d_out, int out_size, void* d_ws, size_t ws_size,
                              hipStream_t stream) {
    const float* x      = (const float*)d_in[0];
    const int*   ei     = (const int*)d_in[1];
    const int*   batch  = (const int*)d_in[2];
    const float* enc_W  = (const float*)d_in[3];
    const float* enc_b  = (const float*)d_in[4];
    const float* W1     = (const float*)d_in[5];
    // d_in[6] = b1, d_in[10] = b2: cancel in the following BN (mean shift)
    const float* g1     = (const float*)d_in[7];
    const float* be1    = (const float*)d_in[8];
    const float* W2     = (const float*)d_in[9];
    const float* eps_g  = (const float*)d_in[11];
    const float* bn_g   = (const float*)d_in[12];
    const float* bn_b   = (const float*)d_in[13];
    const float* cls_W  = (const float*)d_in[14];
    const float* cls_b  = (const float*)d_in[15];
    float* out = (float*)d_out;

    _Float16* Wt    = (_Float16*)d_ws;                 // 12 x HD x HD fp16
    float* bufZ     = (float*)(Wt + 12 * HD * HD);     // NN*HD fp32 (aggr out)
    float* bufT     = bufZ + NN * HD;                  // NN*HD fp32 (gemm1 out)
    _Float16* bufU0 = (_Float16*)(bufT + NN * HD);     // NN*64 fp16 (u, ch 0-63)
    _Float16* bufU1 = bufU0 + NN * 64;                 // NN*64 fp16 (u, ch 64-127)
    int2* brec      = (int2*)(bufU1 + NN * 64);        // NB x BCAP records
    float* pq       = (float*)(brec + NB * BCAP);      // 2*HD
    float* av       = pq + 2 * HD;                     // NN
    float* dv       = av + NN;                         // NN
    float* stats    = dv + NN;                         // 6 units x NR x 256
    float* scal     = stats + 6 * NR * 256;            // 8
    int* gcur       = (int*)(scal + 8);                // NB bucket cursors
    int* row_ptr    = gcur + NB;                       // NN+1
    int* csr_src    = row_ptr + NN + 1;                // NE

    // stats | scal | gcur contiguous: one memset
    hipMemsetAsync(stats, 0, (6 * NR * 256 + 8 + NB) * sizeof(int), stream);

    dim3 b256(256);
    k_setup<<<549, b256, 0, stream>>>(enc_W, enc_b, W1, W2, ei, Wt, pq, brec, gcur);
    k_csr<<<NB, b256, 0, stream>>>(brec, gcur, x, eps_g, row_ptr, csr_src, av, dv, scal);

    const int aggr_blocks = (NN * 16 + 255) / 256;   // 1250 (half-major order)
    const int gemm_blocks = NN / 32;                 // 625

#define STU(u) (stats + (u) * NR * 256)

    // ---- layer 0: rank-2 collapse (no enc, no aggr, no gemm1) ----
    k_gemmA<<<gemm_blocks, b256, 0, stream>>>(
        av, dv, pq, scal, g1, be1,
        Wt + 1 * HD * HD, Wt + 7 * HD * HD, bufU0, bufU1, STU(1));

    // ---- layers 1,2 ----
    for (int l = 1; l < NL; l++) {
        _Float16* Whi1 = Wt + (2 * l) * HD * HD;
        _Float16* Wlo1 = Wt + (6 + 2 * l) * HD * HD;
        _Float16* Whi2 = Wt + (2 * l + 1) * HD * HD;
        _Float16* Wlo2 = Wt + (6 + 2 * l + 1) * HD * HD;
        k_aggr<<<aggr_blocks, b256, 0, stream>>>(
            row_ptr, csr_src, bufU0, bufU1, STU(2 * l - 1),
            bn_g + (l - 1) * HD, bn_b + (l - 1) * HD, eps_g, l, bufZ);
        k_gemm<false, false><<<gemm_blocks, b256, 0, stream>>>(
            bufZ, Whi1, Wlo1, nullptr, nullptr, nullptr, bufT, nullptr, STU(2 * l));
        k_gemm<true, true><<<gemm_blocks, b256, 0, stream>>>(
            bufT, Whi2, Wlo2, STU(2 * l), g1 + l * HD, be1 + l * HD,
            bufU0, bufU1, STU(2 * l + 1));
    }
    k_pool<<<NG, b256, 0, stream>>>(bufU0, bufU1, STU(5),
                                    bn_g + 2 * HD, bn_b + 2 * HD,
                                    batch, cls_W, cls_b, out);
}

// Round 18
// 289.730 us; speedup vs baseline: 1.0794x; 1.0794x over previous
//
#include <hip/hip_runtime.h>

#define NN 20000
#define NE 640000
#define HD 128
#define NL 3
#define NG 128
#define NC 2
#define BN_EPS 1e-5f
#define NR 4            // stat replicas (atomic spread)
#define AST 136
#define NB 157          // dst buckets (dst >> 7), 128 nodes each
#define BCAP 6144       // records per bucket (mean 4076, +32 sigma)

typedef __attribute__((ext_vector_type(4))) float f32x4;
typedef __attribute__((ext_vector_type(8))) _Float16 f16x8;

// ---------- fused setup: weight fp16-split prep + p/q + edge bucketize ----------
__global__ void k_setup(const float* __restrict__ encW, const float* __restrict__ encb,
                        const float* __restrict__ W1, const float* __restrict__ W2,
                        const int* __restrict__ ei,
                        _Float16* __restrict__ Wt, float* __restrict__ pq,
                        int2* __restrict__ brec, int* __restrict__ gcur) {
    __shared__ int cnt[NB];
    __shared__ int base[NB];
    int b = blockIdx.x, tid = threadIdx.x;
    if (b < 48) {
        int t = b * 256 + tid;                 // 6*2048 = 12288
        if (t >= 6 * 2048) return;
        int mat = t >> 11;
        int rem = t & 2047;
        int n  = rem >> 4;
        int k0 = (rem & 15) * 8;
        int l  = mat >> 1;
        const float* src = (mat & 1) ? (W2 + l * HD * HD) : (W1 + l * HD * HD);
        _Float16* dhi = Wt + mat * HD * HD;
        _Float16* dlo = Wt + (6 + mat) * HD * HD;
        f16x8 hi, lo;
#pragma unroll
        for (int j = 0; j < 8; j++) {
            float w = src[(k0 + j) * HD + n];
            _Float16 hh = (_Float16)w;
            hi[j] = hh;
            lo[j] = (_Float16)((w - (float)hh) * 1024.0f);
        }
        *(f16x8*)&dhi[n * HD + k0] = hi;
        *(f16x8*)&dlo[n * HD + k0] = lo;
    } else if (b == 48) {
        if (tid < HD) {
            float ps = 0.f, qs = 0.f;
            for (int k = 0; k < HD; k++) {
                float w = W1[k * HD + tid];
                ps = fmaf(encW[k], w, ps);
                qs = fmaf(encb[k], w, qs);
            }
            pq[tid] = ps;
            pq[HD + tid] = qs;
        }
    } else {
        int bb = b - 49;                       // 0..499, 1280 edges each (exact)
        for (int i = tid; i < NB; i += 256) cnt[i] = 0;
        __syncthreads();
        int src[5], dst[5];
#pragma unroll
        for (int j = 0; j < 5; j++) {
            int e = bb * 1280 + j * 256 + tid;
            src[j] = ei[e];
            dst[j] = ei[NE + e];
            atomicAdd(&cnt[dst[j] >> 7], 1);
        }
        __syncthreads();
        for (int i = tid; i < NB; i += 256) {
            base[i] = atomicAdd(&gcur[i], cnt[i]);
            cnt[i] = 0;
        }
        __syncthreads();
#pragma unroll
        for (int j = 0; j < 5; j++) {
            int bk = dst[j] >> 7;
            int pos = base[bk] + atomicAdd(&cnt[bk], 1);
            brec[bk * BCAP + pos] = make_int2(src[j], dst[j]);
        }
    }
}

// ---------- CSR finalize + layer-0 scalar aggregation, per bucket ----------
__global__ void k_csr(const int2* __restrict__ brec, const int* __restrict__ gcur,
                      const float* __restrict__ x, const float* __restrict__ eps_gin,
                      int* __restrict__ row_ptr, int* __restrict__ csr_src,
                      float* __restrict__ av, float* __restrict__ dv,
                      float* __restrict__ scal) {
    __shared__ int lc[128];
    __shared__ float sx[128];
    __shared__ int pfx[128];
    __shared__ int sbase[4];
    __shared__ int cur[128];
    int b = blockIdx.x, tid = threadIdx.x;
    if (tid < 128) { lc[tid] = 0; sx[tid] = 0.f; }
    __syncthreads();
    int nrec = gcur[b];
    const int2* rec = brec + b * BCAP;
    for (int r = tid; r < nrec; r += 256) {
        int2 rc = rec[r];
        atomicAdd(&lc[rc.y & 127], 1);
        atomicAdd(&sx[rc.y & 127], x[rc.x]);
    }
    int v = (tid < b) ? gcur[tid] : 0;     // b <= 156 < 256
    v += __shfl_xor(v, 1);  v += __shfl_xor(v, 2);  v += __shfl_xor(v, 4);
    v += __shfl_xor(v, 8);  v += __shfl_xor(v, 16); v += __shfl_xor(v, 32);
    if ((tid & 63) == 0) sbase[tid >> 6] = v;
    __syncthreads();
    int base0 = sbase[0] + sbase[1] + sbase[2] + sbase[3];
    if (tid < 128) pfx[tid] = lc[tid];
    __syncthreads();
    for (int off = 1; off < 128; off <<= 1) {
        int t = (tid < 128 && tid >= off) ? pfx[tid - off] : 0;
        __syncthreads();
        if (tid < 128) pfx[tid] += t;
        __syncthreads();
    }
    if (tid < 128) {
        int node = b * 128 + tid;
        int e = base0 + pfx[tid] - lc[tid];   // exclusive
        if (node < NN) { row_ptr[node] = e; cur[tid] = e; }
    }
    if (b == NB - 1 && tid == 0) row_ptr[NN] = NE;
    __syncthreads();
    for (int r = tid; r < nrec; r += 256) {
        int2 rc = rec[r];
        int pos = atomicAdd(&cur[rc.y & 127], 1);
        csr_src[pos] = rc.x;
    }
    __syncthreads();
    float a = 0.f, d = 0.f;
    if (tid < 128) {
        int node = b * 128 + tid;
        if (node < NN) {
            float e = 1.0f + eps_gin[0];
            a = fmaf(e, x[node], sx[tid]);
            d = e + (float)lc[tid];
            av[node] = a;
            dv[node] = d;
        }
    }
    float vv[5] = { a, d, a * a, d * d, a * d };
#pragma unroll
    for (int j = 0; j < 5; j++) {
        float t = vv[j];
        t += __shfl_xor(t, 1);  t += __shfl_xor(t, 2);  t += __shfl_xor(t, 4);
        t += __shfl_xor(t, 8);  t += __shfl_xor(t, 16); t += __shfl_xor(t, 32);
        vv[j] = t;
    }
    if ((tid & 63) == 0 && tid < 128)
#pragma unroll
        for (int j = 0; j < 5; j++) atomicAdd(&scal[j], vv[j]);
}

// ---------- layer-0 GEMM2: rank-2 A, analytic BN, 3-term split, 32-row tile ----------
__global__ __launch_bounds__(256) void k_gemmA(
    const float* __restrict__ av, const float* __restrict__ dv,
    const float* __restrict__ pq, const float* __restrict__ scal,
    const float* __restrict__ gamma, const float* __restrict__ beta,
    const _Float16* __restrict__ Whi, const _Float16* __restrict__ Wlo,
    _Float16* __restrict__ out0, _Float16* __restrict__ out1,
    float* __restrict__ stat_out) {
    __shared__ __align__(16) _Float16 AsH[32 * AST];
    __shared__ __align__(16) _Float16 AsL[32 * AST];
    int tid  = threadIdx.x;
    int wave = tid >> 6, lane = tid & 63;
    int quad = lane >> 4, l16 = lane & 15;
    int r0   = blockIdx.x * 32;               // 625 blocks, no guards
    int n0w  = wave * 32;
    int rep  = (blockIdx.x & (NR - 1)) * 256;

    f16x8 bhi[2][4], blo[2][4];
#pragma unroll
    for (int nt = 0; nt < 2; nt++) {
        int n = n0w + nt * 16 + l16;
#pragma unroll
        for (int kq = 0; kq < 4; kq++) {
            int k = kq * 32 + quad * 8;
            bhi[nt][kq] = *(const f16x8*)&Whi[n * HD + k];
            blo[nt][kq] = *(const f16x8*)&Wlo[n * HD + k];
        }
    }

    {
        int c8 = (tid & 15) * 8;
        int nl = tid >> 4;
        float Sa = scal[0], Sd = scal[1], Saa = scal[2], Sdd = scal[3], Sad = scal[4];
        float pj[8], qj[8], sc[8], sh[8];
#pragma unroll
        for (int j = 0; j < 8; j++) {
            float P = pq[c8 + j], Q = pq[HD + c8 + j];
            pj[j] = P; qj[j] = Q;
            float mu  = (Sa * P + Sd * Q) * (1.0f / NN);
            float ex2 = (Saa * P * P + 2.f * Sad * P * Q + Sdd * Q * Q) * (1.0f / NN);
            float var = ex2 - mu * mu;
            float g = gamma[c8 + j] * rsqrtf(var + BN_EPS);
            sc[j] = g;
            sh[j] = beta[c8 + j] - g * mu;
        }
#pragma unroll
        for (int i = 0; i < 2; i++) {
            int r = i * 16 + nl;
            int row = r0 + r;
            float a = av[row], d = dv[row];
            f16x8 hh, ll;
#pragma unroll
            for (int j = 0; j < 8; j++) {
                float t0 = fmaf(a, pj[j], d * qj[j]);
                float v = fmaxf(fmaf(sc[j], t0, sh[j]), 0.f);
                _Float16 h = (_Float16)v;
                hh[j] = h;
                ll[j] = (_Float16)((v - (float)h) * 512.0f);
            }
            *(f16x8*)&AsH[r * AST + c8] = hh;
            *(f16x8*)&AsL[r * AST + c8] = ll;
        }
    }
    __syncthreads();

    f32x4 ahh[2][2], ahl[2][2], alh[2][2];
#pragma unroll
    for (int mt = 0; mt < 2; mt++)
#pragma unroll
        for (int nt = 0; nt < 2; nt++)
#pragma unroll
            for (int e2 = 0; e2 < 4; e2++) {
                ahh[mt][nt][e2] = 0.f; ahl[mt][nt][e2] = 0.f; alh[mt][nt][e2] = 0.f;
            }

#pragma unroll
    for (int mt = 0; mt < 2; mt++) {
        int mrow = mt * 16 + l16;
#pragma unroll
        for (int kq = 0; kq < 4; kq++) {
            f16x8 ah = *(const f16x8*)&AsH[mrow * AST + kq * 32 + quad * 8];
            f16x8 al = *(const f16x8*)&AsL[mrow * AST + kq * 32 + quad * 8];
#pragma unroll
            for (int nt = 0; nt < 2; nt++) {
                ahh[mt][nt] = __builtin_amdgcn_mfma_f32_16x16x32_f16(ah, bhi[nt][kq], ahh[mt][nt], 0, 0, 0);
                ahl[mt][nt] = __builtin_amdgcn_mfma_f32_16x16x32_f16(ah, blo[nt][kq], ahl[mt][nt], 0, 0, 0);
                alh[mt][nt] = __builtin_amdgcn_mfma_f32_16x16x32_f16(al, bhi[nt][kq], alh[mt][nt], 0, 0, 0);
            }
        }
    }

    float s[2] = { 0.f, 0.f }, q[2] = { 0.f, 0.f };
#pragma unroll
    for (int mt = 0; mt < 2; mt++) {
        int rbase = r0 + mt * 16 + quad * 4;
#pragma unroll
        for (int rr = 0; rr < 4; rr++) {
            int row = rbase + rr;
#pragma unroll
            for (int nt = 0; nt < 2; nt++) {
                float v = ahh[mt][nt][rr] + ahl[mt][nt][rr] * (1.0f / 1024.0f)
                        + alh[mt][nt][rr] * (1.0f / 512.0f);
                int col = n0w + nt * 16 + l16;
                _Float16* dst = (col < 64) ? out0 : out1;
                dst[row * 64 + (col & 63)] = (_Float16)v;
                s[nt] += v;
                q[nt] = fmaf(v, v, q[nt]);
            }
        }
    }
#pragma unroll
    for (int nt = 0; nt < 2; nt++) {
        float ss = s[nt], qq = q[nt];
        ss += __shfl_xor(ss, 16); ss += __shfl_xor(ss, 32);
        qq += __shfl_xor(qq, 16); qq += __shfl_xor(qq, 32);
        if (lane < 16) {
            atomicAdd(&stat_out[rep + n0w + nt * 16 + lane], ss);
            atomicAdd(&stat_out[rep + 128 + n0w + nt * 16 + lane], qq);
        }
    }
}

// ---------- aggregation: channel-halved fp16 gather, 8-deep unroll ----------
// Grid 1250: blocks [0,625) process half 0 (ch 0-63), [625,1250) half 1.
__global__ void k_aggr(const int* __restrict__ row_ptr, const int* __restrict__ csr_src,
                       const _Float16* __restrict__ u0, const _Float16* __restrict__ u1,
                       const float* __restrict__ stat_in,
                       const float* __restrict__ gamma, const float* __restrict__ beta,
                       const float* __restrict__ eps_gin, int l,
                       float* __restrict__ z) {
    int i = blockIdx.x * blockDim.x + threadIdx.x;   // 2 * NN*8
    if (i >= NN * 16) return;
    int half = (i >= NN * 8) ? 1 : 0;
    int j    = i - half * NN * 8;
    int n    = j >> 3;
    int c8in = (j & 7) * 8;
    int c8   = half * 64 + c8in;
    const _Float16* u = half ? u1 : u0;
    float e = 1.0f + eps_gin[l];
    float sc[8], sh[8];
#pragma unroll
    for (int jj = 0; jj < 8; jj++) {
        float ssum = 0.f, ssq = 0.f;
#pragma unroll
        for (int r = 0; r < NR; r++) {
            ssum += stat_in[r * 256 + c8 + jj];
            ssq  += stat_in[r * 256 + 128 + c8 + jj];
        }
        float mu  = ssum * (1.0f / NN);
        float var = ssq * (1.0f / NN) - mu * mu;
        float a = gamma[c8 + jj] * rsqrtf(var + BN_EPS);
        sc[jj] = a;
        sh[jj] = beta[c8 + jj] - a * mu;
    }
    float acc[8];
    {
        f16x8 r = *(const f16x8*)&u[n * 64 + c8in];
#pragma unroll
        for (int jj = 0; jj < 8; jj++)
            acc[jj] = e * fmaxf(fmaf(sc[jj], (float)r[jj], sh[jj]), 0.f);
    }
    int p = row_ptr[n], end = row_ptr[n + 1];
    for (; p + 7 < end; p += 8) {
        f16x8 r[8];
#pragma unroll
        for (int jj = 0; jj < 8; jj++) r[jj] = *(const f16x8*)&u[csr_src[p + jj] * 64 + c8in];
#pragma unroll
        for (int jj = 0; jj < 8; jj++)
#pragma unroll
            for (int q = 0; q < 8; q++)
                acc[q] += fmaxf(fmaf(sc[q], (float)r[jj][q], sh[q]), 0.f);
    }
    for (; p < end; p++) {
        f16x8 r = *(const f16x8*)&u[csr_src[p] * 64 + c8in];
#pragma unroll
        for (int q = 0; q < 8; q++)
            acc[q] += fmaxf(fmaf(sc[q], (float)r[q], sh[q]), 0.f);
    }
    float4 o0 = { acc[0], acc[1], acc[2], acc[3] };
    float4 o1 = { acc[4], acc[5], acc[6], acc[7] };
    *(float4*)&z[n * HD + c8]     = o0;
    *(float4*)&z[n * HD + c8 + 4] = o1;
}

// ---------- fp16-MFMA GEMM, 32-row tile, fp32 A, 3-term split ----------
template <bool BNRELU, bool OUTF16>
__global__ __launch_bounds__(256) void k_gemm(
    const float* __restrict__ A,
    const _Float16* __restrict__ Whi, const _Float16* __restrict__ Wlo,
    const float* __restrict__ stat_in,
    const float* __restrict__ gamma, const float* __restrict__ beta,
    void* __restrict__ outv, _Float16* __restrict__ out1,
    float* __restrict__ stat_out) {
    __shared__ __align__(16) _Float16 AsH[32 * AST];
    __shared__ __align__(16) _Float16 AsL[32 * AST];
    int tid  = threadIdx.x;
    int wave = tid >> 6, lane = tid & 63;
    int quad = lane >> 4, l16 = lane & 15;
    int r0   = blockIdx.x * 32;               // 625 blocks: no guards
    int n0w  = wave * 32;
    int rep  = (blockIdx.x & (NR - 1)) * 256;

    f16x8 bhi[2][4], blo[2][4];
#pragma unroll
    for (int nt = 0; nt < 2; nt++) {
        int n = n0w + nt * 16 + l16;
#pragma unroll
        for (int kq = 0; kq < 4; kq++) {
            int k = kq * 32 + quad * 8;
            bhi[nt][kq] = *(const f16x8*)&Whi[n * HD + k];
            blo[nt][kq] = *(const f16x8*)&Wlo[n * HD + k];
        }
    }

    {
        int c8 = (tid & 15) * 8;
        int nl = tid >> 4;
        float sc[8], sh[8];
        if (BNRELU) {
#pragma unroll
            for (int j = 0; j < 8; j++) {
                float ssum = 0.f, ssq = 0.f;
#pragma unroll
                for (int r = 0; r < NR; r++) {
                    ssum += stat_in[r * 256 + c8 + j];
                    ssq  += stat_in[r * 256 + 128 + c8 + j];
                }
                float mu  = ssum * (1.0f / NN);
                float var = ssq * (1.0f / NN) - mu * mu;
                float a = gamma[c8 + j] * rsqrtf(var + BN_EPS);
                sc[j] = a;
                sh[j] = beta[c8 + j] - a * mu;
            }
        }
#pragma unroll
        for (int i = 0; i < 2; i++) {
            int r = i * 16 + nl;
            int row = r0 + r;
            float4 a0 = *(const float4*)&A[row * HD + c8];
            float4 a1 = *(const float4*)&A[row * HD + c8 + 4];
            float av8[8] = { a0.x, a0.y, a0.z, a0.w, a1.x, a1.y, a1.z, a1.w };
            f16x8 hh, ll;
#pragma unroll
            for (int j = 0; j < 8; j++) {
                float a = av8[j];
                if (BNRELU) a = fmaxf(fmaf(sc[j], a, sh[j]), 0.f);
                _Float16 h = (_Float16)a;
                hh[j] = h;
                ll[j] = (_Float16)((a - (float)h) * 512.0f);
            }
            *(f16x8*)&AsH[r * AST + c8] = hh;
            *(f16x8*)&AsL[r * AST + c8] = ll;
        }
    }
    __syncthreads();

    f32x4 ahh[2][2], ahl[2][2], alh[2][2];
#pragma unroll
    for (int mt = 0; mt < 2; mt++)
#pragma unroll
        for (int nt = 0; nt < 2; nt++)
#pragma unroll
            for (int e2 = 0; e2 < 4; e2++) {
                ahh[mt][nt][e2] = 0.f; ahl[mt][nt][e2] = 0.f; alh[mt][nt][e2] = 0.f;
            }

#pragma unroll
    for (int mt = 0; mt < 2; mt++) {
        int mrow = mt * 16 + l16;
#pragma unroll
        for (int kq = 0; kq < 4; kq++) {
            f16x8 ah = *(const f16x8*)&AsH[mrow * AST + kq * 32 + quad * 8];
            f16x8 al = *(const f16x8*)&AsL[mrow * AST + kq * 32 + quad * 8];
#pragma unroll
            for (int nt = 0; nt < 2; nt++) {
                ahh[mt][nt] = __builtin_amdgcn_mfma_f32_16x16x32_f16(ah, bhi[nt][kq], ahh[mt][nt], 0, 0, 0);
                ahl[mt][nt] = __builtin_amdgcn_mfma_f32_16x16x32_f16(ah, blo[nt][kq], ahl[mt][nt], 0, 0, 0);
                alh[mt][nt] = __builtin_amdgcn_mfma_f32_16x16x32_f16(al, bhi[nt][kq], alh[mt][nt], 0, 0, 0);
            }
        }
    }

    float s[2] = { 0.f, 0.f }, q[2] = { 0.f, 0.f };
#pragma unroll
    for (int mt = 0; mt < 2; mt++) {
        int rbase = r0 + mt * 16 + quad * 4;
#pragma unroll
        for (int rr = 0; rr < 4; rr++) {
            int row = rbase + rr;
#pragma unroll
            for (int nt = 0; nt < 2; nt++) {
                float v = ahh[mt][nt][rr] + ahl[mt][nt][rr] * (1.0f / 1024.0f)
                        + alh[mt][nt][rr] * (1.0f / 512.0f);
                int col = n0w + nt * 16 + l16;
                if (OUTF16) {
                    _Float16* dst = (col < 64) ? (_Float16*)outv : out1;
                    dst[row * 64 + (col & 63)] = (_Float16)v;
                } else {
                    ((float*)outv)[row * HD + col] = v;
                }
                s[nt] += v;
                q[nt] = fmaf(v, v, q[nt]);
            }
        }
    }
#pragma unroll
    for (int nt = 0; nt < 2; nt++) {
        float ss = s[nt], qq = q[nt];
        ss += __shfl_xor(ss, 16); ss += __shfl_xor(ss, 32);
        qq += __shfl_xor(qq, 16); qq += __shfl_xor(qq, 32);
        if (lane < 16) {
            atomicAdd(&stat_out[rep + n0w + nt * 16 + lane], ss);
            atomicAdd(&stat_out[rep + 128 + n0w + nt * 16 + lane], qq);
        }
    }
}

// ---------- pool + classifier (split fp16 u, inline BN) ----------
__global__ __launch_bounds__(256) void k_pool(
    const _Float16* __restrict__ u0, const _Float16* __restrict__ u1,
    const float* __restrict__ stat_in,
    const float* __restrict__ gamma, const float* __restrict__ beta,
    const int* __restrict__ batch, const float* __restrict__ Wc,
    const float* __restrict__ bc, float* __restrict__ out) {
    __shared__ float part[2][HD];
    __shared__ float pooled[HD];
    __shared__ int range[2];
    int g = blockIdx.x;
    int tid = threadIdx.x;
    if (tid < 2) {
        int target = g + tid;
        int lo = 0, hi = NN;
        while (lo < hi) {
            int mid = (lo + hi) >> 1;
            if (batch[mid] < target) lo = mid + 1; else hi = mid;
        }
        range[tid] = lo;
    }
    __syncthreads();
    int start = range[0], end = range[1];
    int c    = tid & (HD - 1);
    int half = tid >> 7;
    const _Float16* uh = (c < 64) ? u0 : u1;
    int cin = c & 63;
    float ssum = 0.f, ssq = 0.f;
#pragma unroll
    for (int r = 0; r < NR; r++) {
        ssum += stat_in[r * 256 + c];
        ssq  += stat_in[r * 256 + 128 + c];
    }
    float mu  = ssum * (1.0f / NN);
    float var = ssq * (1.0f / NN) - mu * mu;
    float sc = gamma[c] * rsqrtf(var + BN_EPS);
    float sh = beta[c] - sc * mu;
    float acc = 0.f;
    for (int n = start + half; n < end; n += 2)
        acc += fmaxf(fmaf(sc, (float)uh[n * 64 + cin], sh), 0.f);
    part[half][c] = acc;
    __syncthreads();
    if (tid < HD) {
        float inv = 1.0f / fmaxf((float)(end - start), 1.0f);
        pooled[tid] = (part[0][tid] + part[1][tid]) * inv;
    }
    __syncthreads();
    if (tid < NC) {
        float a = bc[tid];
        for (int k = 0; k < HD; k++)
            a = fmaf(pooled[k], Wc[k * NC + tid], a);
        out[g * NC + tid] = a;
    }
}

extern "C" void kernel_launch(void* const* d_in, const int* in_sizes, int n_in,
                              void* d_out, int out_size, void* d_ws, size_t ws_size,
                              hipStream_t stream) {
    const float* x      = (const float*)d_in[0];
    const int*   ei     = (const int*)d_in[1];
    const int*   batch  = (const int*)d_in[2];
    const float* enc_W  = (const float*)d_in[3];
    const float* enc_b  = (const float*)d_in[4];
    const float* W1     = (const float*)d_in[5];
    // d_in[6] = b1, d_in[10] = b2: cancel in the following BN (mean shift)
    const float* g1     = (const float*)d_in[7];
    const float* be1    = (const float*)d_in[8];
    const float* W2     = (const float*)d_in[9];
    const float* eps_g  = (const float*)d_in[11];
    const float* bn_g   = (const float*)d_in[12];
    const float* bn_b   = (const float*)d_in[13];
    const float* cls_W  = (const float*)d_in[14];
    const float* cls_b  = (const float*)d_in[15];
    float* out = (float*)d_out;

    _Float16* Wt    = (_Float16*)d_ws;                 // 12 x HD x HD fp16
    float* bufZ     = (float*)(Wt + 12 * HD * HD);     // NN*HD fp32 (aggr out)
    float* bufT     = bufZ + NN * HD;                  // NN*HD fp32 (gemm1 out)
    _Float16* bufU0 = (_Float16*)(bufT + NN * HD);     // NN*64 fp16 (u, ch 0-63)
    _Float16* bufU1 = bufU0 + NN * 64;                 // NN*64 fp16 (u, ch 64-127)
    int2* brec      = (int2*)(bufU1 + NN * 64);        // NB x BCAP records
    float* pq       = (float*)(brec + NB * BCAP);      // 2*HD
    float* av       = pq + 2 * HD;                     // NN
    float* dv       = av + NN;                         // NN
    float* stats    = dv + NN;                         // 6 units x NR x 256
    float* scal     = stats + 6 * NR * 256;            // 8
    int* gcur       = (int*)(scal + 8);                // NB bucket cursors
    int* row_ptr    = gcur + NB;                       // NN+1
    int* csr_src    = row_ptr + NN + 1;                // NE

    hipMemsetAsync(stats, 0, (6 * NR * 256 + 8 + NB) * sizeof(int), stream);

    dim3 b256(256);
    k_setup<<<549, b256, 0, stream>>>(enc_W, enc_b, W1, W2, ei, Wt, pq, brec, gcur);
    k_csr<<<NB, b256, 0, stream>>>(brec, gcur, x, eps_g, row_ptr, csr_src, av, dv, scal);

    const int aggr_blocks = (NN * 16 + 255) / 256;   // 1250 (half-major order)
    const int gemm_blocks = NN / 32;                 // 625

#define STU(u) (stats + (u) * NR * 256)

    // ---- layer 0: rank-2 collapse (no enc, no aggr, no gemm1) ----
    k_gemmA<<<gemm_blocks, b256, 0, stream>>>(
        av, dv, pq, scal, g1, be1,
        Wt + 1 * HD * HD, Wt + 7 * HD * HD, bufU0, bufU1, STU(1));

    // ---- layers 1,2 ----
    for (int l = 1; l < NL; l++) {
        _Float16* Whi1 = Wt + (2 * l) * HD * HD;
        _Float16* Wlo1 = Wt + (6 + 2 * l) * HD * HD;
        _Float16* Whi2 = Wt + (2 * l + 1) * HD * HD;
        _Float16* Wlo2 = Wt + (6 + 2 * l + 1) * HD * HD;
        k_aggr<<<aggr_blocks, b256, 0, stream>>>(
            row_ptr, csr_src, bufU0, bufU1, STU(2 * l - 1),
            bn_g + (l - 1) * HD, bn_b + (l - 1) * HD, eps_g, l, bufZ);
        k_gemm<false, false><<<gemm_blocks, b256, 0, stream>>>(
            bufZ, Whi1, Wlo1, nullptr, nullptr, nullptr, bufT, nullptr, STU(2 * l));
        k_gemm<true, true><<<gemm_blocks, b256, 0, stream>>>(
            bufT, Whi2, Wlo2, STU(2 * l), g1 + l * HD, be1 + l * HD,
            bufU0, bufU1, STU(2 * l + 1));
    }
    k_pool<<<NG, b256, 0, stream>>>(bufU0, bufU1, STU(5),
                                    bn_g + 2 * HD, bn_b + 2 * HD,
                                    batch, cls_W, cls_b, out);
}